// Round 5
// baseline (2537.220 us; speedup 1.0000x reference)
//
#include <hip/hip_runtime.h>
#include <hip/hip_bf16.h>

#define LEAKY(v) ((v) >= 0.0f ? (v) : 0.01f * (v))

// ---------------------------------------------------------------------------
// k_init: ego -> out cols [0,64) (raw; also serves as layer-0 input).
// ---------------------------------------------------------------------------
__global__ void k_init(const float* __restrict__ ego, float* __restrict__ out, int n) {
  int tid = blockIdx.x * blockDim.x + threadIdx.x;
  int total = n * 16;
  int stride = gridDim.x * blockDim.x;
  for (int t = tid; t < total; t += stride) {
    int r = t >> 4, c = (t & 15) * 4;
    float4 v = *(const float4*)(ego + (size_t)r * 64 + c);
    *(float4*)(out + (size_t)r * 176 + c) = v;
  }
}

// ---------------------------------------------------------------------------
// CSR build: histogram -> single-block scan -> scatter (col,val as int2)
// ---------------------------------------------------------------------------
__global__ void k_count(const int* __restrict__ erow, int* __restrict__ cnt, int E) {
  int tid = blockIdx.x * blockDim.x + threadIdx.x;
  int stride = gridDim.x * blockDim.x;
  for (int e = tid; e < E; e += stride) atomicAdd(&cnt[erow[e]], 1);
}

__global__ void __launch_bounds__(1024) k_scan(const int* __restrict__ cnt,
                                               int* __restrict__ rp, int n) {
  __shared__ int ssum[1024];
  int t = threadIdx.x;
  int chunk = (n + 1023) >> 10;
  int beg = t * chunk;
  int end = min(beg + chunk, n);
  int s = 0;
  for (int i = beg; i < end; ++i) s += cnt[i];
  ssum[t] = s;
  __syncthreads();
  for (int off = 1; off < 1024; off <<= 1) {
    int v = (t >= off) ? ssum[t - off] : 0;
    __syncthreads();
    ssum[t] += v;
    __syncthreads();
  }
  int excl = (t == 0) ? 0 : ssum[t - 1];
  for (int i = beg; i < end; ++i) {
    rp[i] = excl;
    excl += cnt[i];
  }
  if (t == 1023) rp[n] = excl;
}

__global__ void k_scatter(const int* __restrict__ erow, const int* __restrict__ ecol,
                          const float* __restrict__ ev, int* cur,
                          int2* __restrict__ cv, int E) {
  int tid = blockIdx.x * blockDim.x + threadIdx.x;
  int stride = gridDim.x * blockDim.x;
  for (int e = tid; e < E; e += stride) {
    int r = erow[e];
    int pos = atomicAdd(&cur[r], 1);
    int2 p;
    p.x = ecol[e];
    p.y = __float_as_int(ev[e]);
    cv[pos] = p;
  }
}

// ---------------------------------------------------------------------------
// k_layer: fused SpMM (CSR gather, 4-wide unrolled) + transform.
// One wave per row; lane = feature (f = lane & (DIN-1)).
//   side = sum val_e * xin[col_e]  (registers)
//   xn = leaky((x+side)@W1+b1) + leaky((x*side)@W2+b2)  -> outp (UNnormalized)
// xin = out + col0_in (stride 176), outp = out + col0_out: same buffer,
// disjoint column ranges -> no __restrict__ on either.
// ---------------------------------------------------------------------------
template <int DIN, int DOUT>
__global__ void __launch_bounds__(256) k_layer(
    const int* __restrict__ rp, const int2* __restrict__ cv,
    const float* xin,
    const float* __restrict__ W1, const float* __restrict__ b1,
    const float* __restrict__ W2, const float* __restrict__ b2,
    float* outp, int n) {
  __shared__ float sW1[DIN * DOUT + 64];
  __shared__ float sW2[DIN * DOUT + 64];
  __shared__ float sb[128];
  for (int i = threadIdx.x; i < DIN * DOUT + 64; i += blockDim.x) {
    sW1[i] = (i < DIN * DOUT) ? W1[i] : 0.0f;
    sW2[i] = (i < DIN * DOUT) ? W2[i] : 0.0f;
  }
  if (threadIdx.x < 64) {
    int i = threadIdx.x;
    sb[i] = (i < DOUT) ? b1[i] : 0.0f;
    sb[64 + i] = (i < DOUT) ? b2[i] : 0.0f;
  }
  __syncthreads();

  int row = (int)((blockIdx.x * (unsigned)blockDim.x + threadIdx.x) >> 6);
  int lane = threadIdx.x & 63;
  if (row >= n) return;

  int f = lane & (DIN - 1);
  int beg = rp[row], end = rp[row + 1];
  float acc = 0.0f;
  int e = beg;
  for (; e + 4 <= end; e += 4) {
    int2 q0 = cv[e], q1 = cv[e + 1], q2 = cv[e + 2], q3 = cv[e + 3];
    float g0 = xin[(size_t)q0.x * 176 + f];
    float g1 = xin[(size_t)q1.x * 176 + f];
    float g2 = xin[(size_t)q2.x * 176 + f];
    float g3 = xin[(size_t)q3.x * 176 + f];
    acc = fmaf(__int_as_float(q0.y), g0, acc);
    acc = fmaf(__int_as_float(q1.y), g1, acc);
    acc = fmaf(__int_as_float(q2.y), g2, acc);
    acc = fmaf(__int_as_float(q3.y), g3, acc);
  }
  for (; e < end; ++e) {
    int2 q = cv[e];
    acc = fmaf(__int_as_float(q.y), xin[(size_t)q.x * 176 + f], acc);
  }

  float xv = (lane < DIN) ? xin[(size_t)row * 176 + lane] : 0.0f;
  float a = xv + acc;
  float m = xv * acc;

  float acc1 = sb[lane], acc2 = sb[64 + lane];
#pragma unroll
  for (int k = 0; k < DIN; ++k) {
    float ak = __shfl(a, k), mk = __shfl(m, k);
    acc1 = fmaf(ak, sW1[k * DOUT + lane], acc1);
    acc2 = fmaf(mk, sW2[k * DOUT + lane], acc2);
  }
  float xn = LEAKY(acc1) + LEAKY(acc2);
  if (lane < DOUT) outp[(size_t)row * 176 + lane] = xn;
}

// ---------------------------------------------------------------------------
// k_norm: final pass, L2-normalize cols [64,128), [128,160), [160,176)
// in place. One wave per row.
// ---------------------------------------------------------------------------
__global__ void __launch_bounds__(256) k_norm(float* out, int n) {
  int row = (int)((blockIdx.x * (unsigned)blockDim.x + threadIdx.x) >> 6);
  int lane = threadIdx.x & 63;
  if (row >= n) return;
  float* r = out + (size_t)row * 176;
  float a = r[64 + lane];
  float b = (lane < 48) ? r[128 + lane] : 0.0f;
  float sa = a * a;
  float sb_ = (lane < 32) ? b * b : 0.0f;
  float sc = (lane >= 32 && lane < 48) ? b * b : 0.0f;
#pragma unroll
  for (int off = 32; off; off >>= 1) {
    sa += __shfl_xor(sa, off);
    sb_ += __shfl_xor(sb_, off);
    sc += __shfl_xor(sc, off);
  }
  float ia = 1.0f / fmaxf(sqrtf(sa), 1e-12f);
  float ib = 1.0f / fmaxf(sqrtf(sb_), 1e-12f);
  float ic = 1.0f / fmaxf(sqrtf(sc), 1e-12f);
  r[64 + lane] = a * ia;
  if (lane < 48) r[128 + lane] = b * ((lane < 32) ? ib : ic);
}

// ---------------------------------------------------------------------------
extern "C" void kernel_launch(void* const* d_in, const int* in_sizes, int n_in,
                              void* d_out, int out_size, void* d_ws, size_t ws_size,
                              hipStream_t stream) {
  const float* ego = (const float*)d_in[0];
  const int* erow = (const int*)d_in[1];
  const int* ecol = (const int*)d_in[2];
  const float* ev = (const float*)d_in[3];
  const int n = in_sizes[0] / 64;  // 160000
  const int E = in_sizes[1];       // 5120000

  float* out = (float*)d_out;  // [n, 176] f32

  // ws layout: cv[E] | rp[n+1] | cnt[n] | cur[n]   (~43 MB, proven budget)
  int2* cv = (int2*)d_ws;
  int* rp = (int*)(cv + E);
  int* cnt = rp + n + 1;
  int* cur = cnt + n;

  const int rblocks = (n + 3) / 4;  // one wave per row, 4 waves/block

  k_init<<<2048, 256, 0, stream>>>(ego, out, n);
  hipMemsetAsync(cnt, 0, (size_t)n * sizeof(int), stream);
  k_count<<<2048, 256, 0, stream>>>(erow, cnt, E);
  k_scan<<<1, 1024, 0, stream>>>(cnt, rp, n);
  hipMemcpyAsync(cur, rp, (size_t)n * sizeof(int), hipMemcpyDeviceToDevice, stream);
  k_scatter<<<2048, 256, 0, stream>>>(erow, ecol, ev, cur, cv, E);

  k_layer<64, 64><<<rblocks, 256, 0, stream>>>(
      rp, cv, out, (const float*)d_in[4], (const float*)d_in[5],
      (const float*)d_in[6], (const float*)d_in[7], out + 64, n);
  k_layer<64, 32><<<rblocks, 256, 0, stream>>>(
      rp, cv, out + 64, (const float*)d_in[8], (const float*)d_in[9],
      (const float*)d_in[10], (const float*)d_in[11], out + 128, n);
  k_layer<32, 16><<<rblocks, 256, 0, stream>>>(
      rp, cv, out + 128, (const float*)d_in[12], (const float*)d_in[13],
      (const float*)d_in[14], (const float*)d_in[15], out + 160, n);

  k_norm<<<rblocks, 256, 0, stream>>>(out, n);
}